// Round 18
// baseline (183.012 us; speedup 1.0000x reference)
//
#include <hip/hip_runtime.h>

#define NPTS   2048
#define TPB    384    // 6 waves/block; 2 cells/thread; window 768
#define WIN    768    // own 512 + 128 wedge each side (uniform, clamped)
#define TCHUNK 125    // steps/launch; wedge 128 > 125+2 cone -> own exact

typedef float v2f __attribute__((ext_vector_type(2)));

// Barrier WITHOUT the vmcnt(0) drain __syncthreads() would emit:
// LDS writes must be visible (lgkmcnt), global stores may stay in flight.
#define EDGE_BARRIER() do {                                   \
    asm volatile("s_waitcnt lgkmcnt(0)" ::: "memory");        \
    __builtin_amdgcn_s_barrier();                             \
    asm volatile("" ::: "memory");                            \
} while (0)

__device__ __forceinline__ v2f s2(float x) { v2f v; v.x = x; v.y = x; return v; }

// packed fma: lowers to v_pk_fma_f32 (2 f32 FMA / lane / instr)
__device__ __forceinline__ v2f fma2(v2f a, v2f b, v2f c) {
#if __has_builtin(__builtin_elementwise_fma)
    return __builtin_elementwise_fma(a, b, c);
#else
    v2f r; r.x = fmaf(a.x, b.x, c.x); r.y = fmaf(a.y, b.y, c.y); return r;
#endif
}

// g = 0.5*f(u) = u*(0.75 + u*(9.375 + u*(-25.25 + u*(18.75 - 3.125 u^2))))
// p = f'(u)    = 1.5 + u*(37.5 + u*(-151.5 + u*(150 - 37.5 u^2)))
__device__ __forceinline__ void eval_gp2(v2f u, v2f& g, v2f& p) {
    const v2f uu = u * u;
    v2f gg = fma2(uu, s2(-3.125f), s2(18.75f));
    gg = fma2(u, gg, s2(-25.25f));
    gg = fma2(u, gg, s2(9.375f));
    gg = fma2(u, gg, s2(0.75f));
    g = u * gg;
    v2f pp = fma2(uu, s2(-37.5f), s2(150.0f));
    pp = fma2(u, pp, s2(-151.5f));
    pp = fma2(u, pp, s2(37.5f));
    p = fma2(u, pp, s2(1.5f));
}

// 4 blocks/row x 128 rows = 512 blocks -> 2 independent blocks per CU
// (two uncorrelated barrier domains overlap each other's serial chains).
// Block (r,h): window = 768 cells at wb(h), own 512 cells at 512*h.
// Wedge >= 128 cells each interior side; junk advances 1 cell/step ->
// own cells bit-exact for <=125 steps/launch. Time-chunked via 4 launches
// (state round-trips through out rows; same-stream ordering).
__global__ __launch_bounds__(TPB) void lxf_tc4(
    const float* __restrict__ srcrow, float* __restrict__ out,
    int nbatch, int t0, int nsub, int copy0)
{
    __shared__ float Ub[2][WIN];   // u
    __shared__ float Gb[2][WIN];   // g = 0.5*f(u)
    __shared__ float Pb[2][WIN];   // p = f'(u)

    const int blk = blockIdx.x;
    const int r   = blk >> 2;            // row
    const int h   = blk & 3;             // quarter index
    const int tid = threadIdx.x;
    const int c0  = 2 * tid;             // local first cell
    // window bases: 0, 384, 896, 1280 (own region 512*h .. 512*h+512)
    const int wb  = (h == 0) ? 0 : ((h == 1) ? 384 : ((h == 2) ? 896 : 1280));
    const int own_lo = 512 * h - wb;     // 0,128,128,256
    const float lam = 0.1024f;           // DT/DX (exact in f32)

    const bool st  = (c0 >= own_lo) && (c0 < own_lo + 512);
    const bool bcL = (h == 0) && (tid == 0);            // global cell 0
    const bool bcR = (h == 3) && (tid == TPB - 1);      // global cell 2047
    // aligned halo-pair bases; window-edge clamps read junk that stays in
    // the wedge cone (or is overridden by the bc at true boundaries)
    const int  il  = (tid == 0)       ? 0       : c0 - 2;
    const int  ir  = (tid == TPB - 1) ? WIN - 2 : c0 + 2;

    // ---- load state at t0, eval, publish buf 0 (window within row) ----
    const size_t stride = (size_t)nbatch * NPTS;    // floats per step
    v2f uv = *reinterpret_cast<const v2f*>(srcrow + (size_t)r * NPTS + wb + c0);
    v2f gv, pv;
    eval_gp2(uv, gv, pv);

    float* sp = out + (size_t)t0 * stride + (size_t)r * NPTS + (wb + c0);
    if (copy0 && st) *reinterpret_cast<v2f*>(sp) = uv;   // t=0 copy

    *reinterpret_cast<v2f*>(&Ub[0][c0]) = uv;
    *reinterpret_cast<v2f*>(&Gb[0][c0]) = gv;
    *reinterpret_cast<v2f*>(&Pb[0][c0]) = pv;
    EDGE_BARRIER();

    float* dstw = sp;

#define STEP(CUR, NXT) do {                                              \
    dstw += stride;                                                      \
    const v2f uLp = *reinterpret_cast<const v2f*>(&Ub[CUR][il]);         \
    const v2f uRp = *reinterpret_cast<const v2f*>(&Ub[CUR][ir]);         \
    const v2f gLp = *reinterpret_cast<const v2f*>(&Gb[CUR][il]);         \
    const v2f gRp = *reinterpret_cast<const v2f*>(&Gb[CUR][ir]);         \
    const v2f pLp = *reinterpret_cast<const v2f*>(&Pb[CUR][il]);         \
    const v2f pRp = *reinterpret_cast<const v2f*>(&Pb[CUR][ir]);         \
    const float uL = uLp.y, gL = gLp.y, pL = pLp.y;                      \
    const float uR = uRp.x, gR = gRp.x, pR = pRp.x;                      \
    const float aL = fmaxf(fabsf(pL), fabsf(pv.x));                      \
    const float aM = fmaxf(fabsf(pv.x), fabsf(pv.y));                    \
    const float aR = fmaxf(fabsf(pv.y), fabsf(pR));                      \
    const float fhL = fmaf(-0.5f * aL, uv.x - uL, gL + gv.x);            \
    const float fhM = fmaf(-0.5f * aM, uv.y - uv.x, gv.x + gv.y);        \
    const float fhR = fmaf(-0.5f * aR, uR - uv.y, gv.y + gR);            \
    float n0 = fmaf(-lam, fhM - fhL, uv.x);                              \
    float n1 = fmaf(-lam, fhR - fhM, uv.y);                              \
    if (bcL) n0 = n1;   /* u[0]   = u[1]   */                            \
    if (bcR) n1 = n0;   /* u[N-1] = u[N-2] */                            \
    uv.x = n0; uv.y = n1;                                                \
    eval_gp2(uv, gv, pv);                                                \
    *reinterpret_cast<v2f*>(&Ub[NXT][c0]) = uv;                          \
    *reinterpret_cast<v2f*>(&Gb[NXT][c0]) = gv;                          \
    *reinterpret_cast<v2f*>(&Pb[NXT][c0]) = pv;                          \
    if (st) *reinterpret_cast<v2f*>(dstw) = uv;                          \
    EDGE_BARRIER();                                                      \
} while (0)

    const int P2 = nsub >> 1;
    for (int i = 0; i < P2; ++i) {
        STEP(0, 1);
        STEP(1, 0);
    }
    if (nsub & 1) STEP(0, 1);
#undef STEP
}

extern "C" void kernel_launch(void* const* d_in, const int* in_sizes, int n_in,
                              void* d_out, int out_size, void* d_ws, size_t ws_size,
                              hipStream_t stream) {
    const float* init = (const float*)d_in[0];
    float* out = (float*)d_out;

    const int nbatch = in_sizes[0] / NPTS;       // 128
    const int nsteps = out_size / in_sizes[0];   // 500
    const int S = nsteps - 1;                    // 499 advance steps
    const size_t stride = (size_t)nbatch * NPTS;

    int t0 = 0;
    int first = 1;
    while (t0 < S) {
        int nsub = S - t0;
        if (nsub > TCHUNK) nsub = TCHUNK;
        const float* srcrow = first ? init : (out + (size_t)t0 * stride);
        hipLaunchKernelGGL(lxf_tc4, dim3(4 * nbatch), dim3(TPB), 0, stream,
                           srcrow, out, nbatch, t0, nsub, first);
        t0 += nsub;
        first = 0;
    }
}

// Round 19
// 160.346 us; speedup vs baseline: 1.1414x; 1.1414x over previous
//
#include <hip/hip_runtime.h>

#define NPTS 2048
#define TPB  768    // 12 waves/block; 2 cells/thread; capacity 1536
#define CAP  1536   // own 1024 + 512 ghost wedge (>= 499 steps of cone)

typedef float v2f __attribute__((ext_vector_type(2)));

// Barrier WITHOUT the vmcnt(0) drain __syncthreads() would emit:
// LDS writes must be visible (lgkmcnt), global stores may stay in flight.
#define EDGE_BARRIER() do {                                   \
    asm volatile("s_waitcnt lgkmcnt(0)" ::: "memory");        \
    __builtin_amdgcn_s_barrier();                             \
    asm volatile("" ::: "memory");                            \
} while (0)

__device__ __forceinline__ v2f s2(float x) { v2f v; v.x = x; v.y = x; return v; }

// packed fma: lowers to v_pk_fma_f32 (2 f32 FMA / lane / instr)
__device__ __forceinline__ v2f fma2(v2f a, v2f b, v2f c) {
#if __has_builtin(__builtin_elementwise_fma)
    return __builtin_elementwise_fma(a, b, c);
#else
    v2f r; r.x = fmaf(a.x, b.x, c.x); r.y = fmaf(a.y, b.y, c.y); return r;
#endif
}

// F = f(u) = u*(1.5 + u*(18.75 + u*(-50.5 + u*(37.5 - 6.25 u^2))))  [= 2g]
// p = f'(u) = 1.5 + u*(37.5 + u*(-151.5 + u*(150 - 37.5 u^2)))
// All F coefficients are exactly 2x the g coefficients (pow2 scale), so the
// flux fh' = fma(-a,du,Fl+Fr) = 2*fh bit-exactly; update uses lam/2.
__device__ __forceinline__ void eval_fp2(v2f u, v2f& F, v2f& p) {
    const v2f uu = u * u;
    v2f ff = fma2(uu, s2(-6.25f), s2(37.5f));
    ff = fma2(u, ff, s2(-50.5f));
    ff = fma2(u, ff, s2(18.75f));
    ff = fma2(u, ff, s2(1.5f));
    F = u * ff;
    v2f pp = fma2(uu, s2(-37.5f), s2(150.0f));
    pp = fma2(u, pp, s2(-151.5f));
    pp = fma2(u, pp, s2(37.5f));
    p = fma2(u, pp, s2(1.5f));
}

// Grid = 2 blocks per row (256 blocks -> all 256 CUs). Block (r,h) evolves
// 1536 cells autonomously: own 1024 + 512-wide ghost wedge toward the
// partner; junk advances 1 cell/step so own cells are bit-exact through
// t=499 (no gating needed - junk, even Inf/NaN, stays in the cone).
// R17-proven body: 3-plane LDS (u,F,p), aligned ds_read_b64 halo pairs.
__global__ __launch_bounds__(TPB) void lxf_split(
    const float* __restrict__ init, float* __restrict__ out,
    int nbatch, int nsteps)
{
    __shared__ float Ub[2][CAP];   // u
    __shared__ float Fb[2][CAP];   // F = f(u)
    __shared__ float Pb[2][CAP];   // p = f'(u)

    const int blk = blockIdx.x;
    const int r   = blk >> 1;            // row
    const int h   = blk & 1;             // 0 -> global [0,1536), 1 -> [512,2048)
    const int tid = threadIdx.x;
    const int c0  = 2 * tid;             // local first cell
    const int gb  = h ? 512 : 0;         // local -> global offset
    const size_t rowoff = (size_t)r * NPTS;
    const float lam2 = 0.0512f;          // (DT/DX)/2, exact in f32

    const bool st  = h ? (c0 >= 512) : (c0 < 1024);      // own-cell store mask
    const bool bcL = (h == 0) && (tid == 0);             // global cell 0
    const bool bcR = (h == 1) && (tid == TPB - 1);       // global cell 2047
    // aligned pair bases: left pair {x[c0-2], x[c0-1]}, right {x[c0+2], x[c0+3]}
    const int  il  = (tid == 0)       ? 0       : c0 - 2;
    const int  ir  = (tid == TPB - 1) ? CAP - 2 : c0 + 2;

    // ---- load init cells, eval F/p, write t=0, publish buf 0 ----
    v2f uv = *reinterpret_cast<const v2f*>(init + rowoff + gb + c0);
    v2f Fv, pv;
    eval_fp2(uv, Fv, pv);

    if (st) *reinterpret_cast<v2f*>(out + rowoff + gb + c0) = uv;

    *reinterpret_cast<v2f*>(&Ub[0][c0]) = uv;
    *reinterpret_cast<v2f*>(&Fb[0][c0]) = Fv;
    *reinterpret_cast<v2f*>(&Pb[0][c0]) = pv;
    EDGE_BARRIER();

    const size_t stride = (size_t)nbatch * NPTS;    // floats per step
    float* dstw = out + rowoff + gb + c0;

#define STEP(CUR, NXT) do {                                              \
    dstw += stride;                                                      \
    const v2f uLp = *reinterpret_cast<const v2f*>(&Ub[CUR][il]);         \
    const v2f uRp = *reinterpret_cast<const v2f*>(&Ub[CUR][ir]);         \
    const v2f FLp = *reinterpret_cast<const v2f*>(&Fb[CUR][il]);         \
    const v2f FRp = *reinterpret_cast<const v2f*>(&Fb[CUR][ir]);         \
    const v2f pLp = *reinterpret_cast<const v2f*>(&Pb[CUR][il]);         \
    const v2f pRp = *reinterpret_cast<const v2f*>(&Pb[CUR][ir]);         \
    const float uL = uLp.y, FL = FLp.y, pL = pLp.y;                      \
    const float uR = uRp.x, FR = FRp.x, pR = pRp.x;                      \
    const float aL = fmaxf(fabsf(pL), fabsf(pv.x));                      \
    const float aM = fmaxf(fabsf(pv.x), fabsf(pv.y));                    \
    const float aR = fmaxf(fabsf(pv.y), fabsf(pR));                      \
    const float fhL = fmaf(-aL, uv.x - uL, FL + Fv.x);                   \
    const float fhM = fmaf(-aM, uv.y - uv.x, Fv.x + Fv.y);               \
    const float fhR = fmaf(-aR, uR - uv.y, Fv.y + FR);                   \
    float n0 = fmaf(-lam2, fhM - fhL, uv.x);                             \
    float n1 = fmaf(-lam2, fhR - fhM, uv.y);                             \
    if (bcL) n0 = n1;   /* u[0]   = u[1]   */                            \
    if (bcR) n1 = n0;   /* u[N-1] = u[N-2] */                            \
    uv.x = n0; uv.y = n1;                                                \
    eval_fp2(uv, Fv, pv);                                                \
    *reinterpret_cast<v2f*>(&Ub[NXT][c0]) = uv;                          \
    *reinterpret_cast<v2f*>(&Fb[NXT][c0]) = Fv;                          \
    *reinterpret_cast<v2f*>(&Pb[NXT][c0]) = pv;                          \
    if (st) *reinterpret_cast<v2f*>(dstw) = uv;                          \
    EDGE_BARRIER();                                                      \
} while (0)

    const int S  = nsteps - 1;   // 499 advance steps
    const int P4 = S >> 2;       // 124 quad-steps
    for (int i = 0; i < P4; ++i) {
        STEP(0, 1);
        STEP(1, 0);
        STEP(0, 1);
        STEP(1, 0);
    }
    const int rem = S & 3;       // 3 when nsteps=500
    if (rem > 0) STEP(0, 1);
    if (rem > 1) STEP(1, 0);
    if (rem > 2) STEP(0, 1);
#undef STEP
}

extern "C" void kernel_launch(void* const* d_in, const int* in_sizes, int n_in,
                              void* d_out, int out_size, void* d_ws, size_t ws_size,
                              hipStream_t stream) {
    const float* init = (const float*)d_in[0];
    float* out = (float*)d_out;

    const int nbatch = in_sizes[0] / NPTS;       // 128
    const int nsteps = out_size / in_sizes[0];   // 500

    hipLaunchKernelGGL(lxf_split, dim3(2 * nbatch), dim3(TPB), 0, stream,
                       init, out, nbatch, nsteps);
}

// Round 20
// 157.934 us; speedup vs baseline: 1.1588x; 1.0153x over previous
//
#include <hip/hip_runtime.h>

#define NPTS 2048
#define TPB  768    // 12 waves/block; 2 cells/thread; capacity 1536
#define CAP  1536   // own 1024 + 512 ghost wedge (>= 499 steps of cone)

typedef float v2f __attribute__((ext_vector_type(2)));

// Barrier WITHOUT the vmcnt(0) drain __syncthreads() would emit:
// LDS writes must be visible (lgkmcnt), global stores may stay in flight.
#define EDGE_BARRIER() do {                                   \
    asm volatile("s_waitcnt lgkmcnt(0)" ::: "memory");        \
    __builtin_amdgcn_s_barrier();                             \
    asm volatile("" ::: "memory");                            \
} while (0)

__device__ __forceinline__ v2f s2(float x) { v2f v; v.x = x; v.y = x; return v; }

// packed fma: lowers to v_pk_fma_f32 (2 f32 FMA / lane / instr)
__device__ __forceinline__ v2f fma2(v2f a, v2f b, v2f c) {
#if __has_builtin(__builtin_elementwise_fma)
    return __builtin_elementwise_fma(a, b, c);
#else
    v2f r; r.x = fmaf(a.x, b.x, c.x); r.y = fmaf(a.y, b.y, c.y); return r;
#endif
}

// g = 0.5*f(u) = u*(0.75 + u*(9.375 + u*(-25.25 + u*(18.75 - 3.125 u^2))))
// p = f'(u)    = 1.5 + u*(37.5 + u*(-151.5 + u*(150 - 37.5 u^2)))
__device__ __forceinline__ void eval_gp2(v2f u, v2f& g, v2f& p) {
    const v2f uu = u * u;
    v2f gg = fma2(uu, s2(-3.125f), s2(18.75f));
    gg = fma2(u, gg, s2(-25.25f));
    gg = fma2(u, gg, s2(9.375f));
    gg = fma2(u, gg, s2(0.75f));
    g = u * gg;
    v2f pp = fma2(uu, s2(-37.5f), s2(150.0f));
    pp = fma2(u, pp, s2(-151.5f));
    pp = fma2(u, pp, s2(37.5f));
    p = fma2(u, pp, s2(1.5f));
}

// Grid = 2 blocks per row (256 blocks -> all 256 CUs). Block (r,h) evolves
// 1536 cells autonomously: own 1024 + 512-wide ghost wedge toward the
// partner; clamp junk advances 1 cell/step so own cells are bit-exact
// through t=499. R8-proven body; halo reads are aligned ds_read_b64 pairs
// (3 reads/step instead of 6 scalar reads).
__global__ __launch_bounds__(TPB) void lxf_split(
    const float* __restrict__ init, float* __restrict__ out,
    int nbatch, int nsteps)
{
    __shared__ float Ub[2][CAP];   // u
    __shared__ float Gb[2][CAP];   // g = 0.5*f(u)
    __shared__ float Pb[2][CAP];   // p = f'(u)

    const int blk = blockIdx.x;
    const int r   = blk >> 1;            // row
    const int h   = blk & 1;             // 0 -> global [0,1536), 1 -> [512,2048)
    const int tid = threadIdx.x;
    const int c0  = 2 * tid;             // local first cell
    const int gb  = h ? 512 : 0;         // local -> global offset
    const size_t rowoff = (size_t)r * NPTS;
    const float lam = 0.1024f;           // DT/DX (exact in f32)

    const bool st  = h ? (c0 >= 512) : (c0 < 1024);      // own-cell store mask
    const bool bcL = (h == 0) && (tid == 0);             // global cell 0
    const bool bcR = (h == 1) && (tid == TPB - 1);       // global cell 2047
    // aligned pair bases: left pair {u[c0-2], u[c0-1]}, right {u[c0+2], u[c0+3]}
    // tid 0 / TPB-1 clamps read garbage halos that are either overridden by
    // the bc or confined to the junk cone (own cells unaffected).
    const int  il  = (tid == 0)       ? 0       : c0 - 2;
    const int  ir  = (tid == TPB - 1) ? CAP - 2 : c0 + 2;
    // cone distance into the wedge (margin 2); active while dist <= rem
    const int dist = h ? (509 - c0) : (c0 - 1025);

    // ---- load init cells, eval g/p, write t=0, publish buf 0 ----
    v2f uv = *reinterpret_cast<const v2f*>(init + rowoff + gb + c0);
    v2f gv, pv;
    eval_gp2(uv, gv, pv);

    if (st) *reinterpret_cast<v2f*>(out + rowoff + gb + c0) = uv;

    *reinterpret_cast<v2f*>(&Ub[0][c0]) = uv;
    *reinterpret_cast<v2f*>(&Gb[0][c0]) = gv;
    *reinterpret_cast<v2f*>(&Pb[0][c0]) = pv;
    EDGE_BARRIER();

    const size_t stride = (size_t)nbatch * NPTS;    // floats per step
    float* dstw = out + rowoff + gb + c0;

#define STEP(CUR, NXT) do {                                              \
    dstw += stride;                                                      \
    if (dist <= rem) {                                                   \
        const v2f uLp = *reinterpret_cast<const v2f*>(&Ub[CUR][il]);     \
        const v2f uRp = *reinterpret_cast<const v2f*>(&Ub[CUR][ir]);     \
        const v2f gLp = *reinterpret_cast<const v2f*>(&Gb[CUR][il]);     \
        const v2f gRp = *reinterpret_cast<const v2f*>(&Gb[CUR][ir]);     \
        const v2f pLp = *reinterpret_cast<const v2f*>(&Pb[CUR][il]);     \
        const v2f pRp = *reinterpret_cast<const v2f*>(&Pb[CUR][ir]);     \
        const float uL = uLp.y, gL = gLp.y, pL = pLp.y;                  \
        const float uR = uRp.x, gR = gRp.x, pR = pRp.x;                  \
        const float aL = fmaxf(fabsf(pL), fabsf(pv.x));                  \
        const float aM = fmaxf(fabsf(pv.x), fabsf(pv.y));                \
        const float aR = fmaxf(fabsf(pv.y), fabsf(pR));                  \
        const float fhL = fmaf(-0.5f * aL, uv.x - uL, gL + gv.x);        \
        const float fhM = fmaf(-0.5f * aM, uv.y - uv.x, gv.x + gv.y);    \
        const float fhR = fmaf(-0.5f * aR, uR - uv.y, gv.y + gR);        \
        float n0 = fmaf(-lam, fhM - fhL, uv.x);                          \
        float n1 = fmaf(-lam, fhR - fhM, uv.y);                          \
        if (bcL) n0 = n1;   /* u[0]   = u[1]   */                        \
        if (bcR) n1 = n0;   /* u[N-1] = u[N-2] */                        \
        uv.x = n0; uv.y = n1;                                            \
        eval_gp2(uv, gv, pv);                                            \
        *reinterpret_cast<v2f*>(&Ub[NXT][c0]) = uv;                      \
        *reinterpret_cast<v2f*>(&Gb[NXT][c0]) = gv;                      \
        *reinterpret_cast<v2f*>(&Pb[NXT][c0]) = pv;                      \
        if (st) *reinterpret_cast<v2f*>(dstw) = uv;                      \
    }                                                                    \
    --rem;                                                               \
    EDGE_BARRIER();                                                      \
} while (0)

    const int S  = nsteps - 1;   // 499 advance steps
    int rem = S - 1;             // steps remaining AFTER the current one
    const int P2 = S >> 1;       // 249
    for (int i = 0; i < P2; ++i) {
        STEP(0, 1);
        STEP(1, 0);
    }
    if (S & 1) STEP(0, 1);
#undef STEP
}

extern "C" void kernel_launch(void* const* d_in, const int* in_sizes, int n_in,
                              void* d_out, int out_size, void* d_ws, size_t ws_size,
                              hipStream_t stream) {
    const float* init = (const float*)d_in[0];
    float* out = (float*)d_out;

    const int nbatch = in_sizes[0] / NPTS;       // 128
    const int nsteps = out_size / in_sizes[0];   // 500

    hipLaunchKernelGGL(lxf_split, dim3(2 * nbatch), dim3(TPB), 0, stream,
                       init, out, nbatch, nsteps);
}